// Round 1
// baseline (26980.753 us; speedup 1.0000x reference)
//
#include <hip/hip_runtime.h>
#include <stdint.h>

typedef __attribute__((ext_vector_type(8))) short bf16x8;
typedef __attribute__((ext_vector_type(4))) float f32x4;
typedef unsigned int u32;

#define TT 512
#define BB 32
#define HH 1024

__device__ __forceinline__ short f2bf(float f) {
  union { float f; u32 u; } v; v.f = f;
  u32 r = v.u + 0x7fffu + ((v.u >> 16) & 1u);
  return (short)(r >> 16);
}
__device__ __forceinline__ float bf2f(short s) {
  union { float f; u32 u; } v; v.u = ((u32)(unsigned short)s) << 16;
  return v.f;
}
__device__ __forceinline__ float sigmoid_(float x) { return 1.f / (1.f + __expf(-x)); }
__device__ __forceinline__ float tanh_(float x) {
  float cx = fminf(fmaxf(x, -15.f), 15.f);
  float e = __expf(2.f * cx);
  return (e - 1.f) / (e + 1.f);
}

// ---------------- fp32 -> bf16 convert ----------------
__global__ void f32_to_bf16_k(const float* __restrict__ in, short* __restrict__ out, int n) {
  int i = (blockIdx.x * blockDim.x + threadIdx.x) * 8;
  if (i + 8 > n) return;
  float4 a = *(const float4*)(in + i);
  float4 b = *(const float4*)(in + i + 4);
  bf16x8 o;
  o[0] = f2bf(a.x); o[1] = f2bf(a.y); o[2] = f2bf(a.z); o[3] = f2bf(a.w);
  o[4] = f2bf(b.x); o[5] = f2bf(b.y); o[6] = f2bf(b.z); o[7] = f2bf(b.w);
  *(bf16x8*)(out + i) = o;
}

// ------- proj GEMM: C[m][n] = sum_k A[m][k]*B[n][k]; bf16 in, bf16 out -------
// M%128==0, N%128==0, K%64==0
__launch_bounds__(256)
__global__ void gemm_bt_k(const short* __restrict__ A, const short* __restrict__ B,
                          short* __restrict__ C, int M, int N, int K) {
  __shared__ short As[128 * 64];
  __shared__ short Bs[128 * 64];
  const int tid = threadIdx.x;
  const int lane = tid & 63;
  const int wave = tid >> 6;
  const int m0 = blockIdx.x * 128, n0 = blockIdx.y * 128;
  const int wm = (wave >> 1) * 64, wn = (wave & 1) * 64;
  f32x4 acc[4][4];
  for (int i = 0; i < 4; i++)
    for (int j = 0; j < 4; j++) acc[i][j] = 0.f;
  bf16x8* Asv = (bf16x8*)As;
  bf16x8* Bsv = (bf16x8*)Bs;
  for (int k0 = 0; k0 < K; k0 += 64) {
    __syncthreads();
    for (int q = 0; q < 4; ++q) {
      int chunk = tid + q * 256;  // 0..1023 chunks of 8 elems (tile = 128x64)
      int row = chunk >> 3, col = (chunk & 7) * 8;
      Asv[chunk] = *(const bf16x8*)(A + (size_t)(m0 + row) * K + k0 + col);
      Bsv[chunk] = *(const bf16x8*)(B + (size_t)(n0 + row) * K + k0 + col);
    }
    __syncthreads();
    for (int ks = 0; ks < 2; ++ks) {
      int kk = ks * 32 + (lane >> 4) * 8;
      bf16x8 af[4], bfr[4];
      for (int i = 0; i < 4; i++) af[i] = *(const bf16x8*)(As + (wm + i * 16 + (lane & 15)) * 64 + kk);
      for (int j = 0; j < 4; j++) bfr[j] = *(const bf16x8*)(Bs + (wn + j * 16 + (lane & 15)) * 64 + kk);
      for (int i = 0; i < 4; i++)
        for (int j = 0; j < 4; j++)
          acc[i][j] = __builtin_amdgcn_mfma_f32_16x16x32_bf16(af[i], bfr[j], acc[i][j], 0, 0, 0);
    }
  }
  const int r4 = (lane >> 4) * 4, nn = lane & 15;
  for (int i = 0; i < 4; i++)
    for (int j = 0; j < 4; j++) {
      int gm = m0 + wm + i * 16 + r4;
      int gn = n0 + wn + j * 16 + nn;
      for (int r = 0; r < 4; r++) C[(size_t)(gm + r) * N + gn] = f2bf(acc[i][j][r]);
    }
}

// ---------------- grid barrier: flag array, all-poll ----------------
__device__ __forceinline__ void gbar(u32* flags, u32 epoch) {
  __syncthreads();
  if (threadIdx.x == 0) {
    __builtin_amdgcn_fence(__ATOMIC_RELEASE, "agent");
    __hip_atomic_store(flags + blockIdx.x, epoch, __ATOMIC_RELAXED, __HIP_MEMORY_SCOPE_AGENT);
  }
  if (threadIdx.x < 64) {
    const int i0 = threadIdx.x * 4;
    for (;;) {
      u32 v0 = __hip_atomic_load(flags + i0 + 0, __ATOMIC_RELAXED, __HIP_MEMORY_SCOPE_AGENT);
      u32 v1 = __hip_atomic_load(flags + i0 + 1, __ATOMIC_RELAXED, __HIP_MEMORY_SCOPE_AGENT);
      u32 v2 = __hip_atomic_load(flags + i0 + 2, __ATOMIC_RELAXED, __HIP_MEMORY_SCOPE_AGENT);
      u32 v3 = __hip_atomic_load(flags + i0 + 3, __ATOMIC_RELAXED, __HIP_MEMORY_SCOPE_AGENT);
      int ok = (v0 >= epoch) & (v1 >= epoch) & (v2 >= epoch) & (v3 >= epoch);
      if (__all(ok)) break;
      __builtin_amdgcn_s_sleep(2);
    }
    if (threadIdx.x == 0) __builtin_amdgcn_fence(__ATOMIC_ACQUIRE, "agent");
  }
  __syncthreads();
}

// ---------------- persistent recurrent kernel (one layer) ----------------
struct RecurArgs {
  const float *Whh, *Wpi, *Wpf, *Wpo;  // fp32 weights in global
  const short* xg;                     // [T*B][4096] bf16 precomputed input proj
  const short* hsrc;                   // h read base (bf16)
  short* hdst;                         // h write base (bf16)
  float* yout;                         // layer1: fp32 y out (d_out); else null
  short* cbf;                          // [B][H] bf16 c exchange
  float* hn_out;                       // [B][H] fp32 final h
  float* cn_out;                       // [B][H] fp32 final c
  u32* flags;                          // 256 barrier flags (pre-zeroed)
  int h_seq;                           // 1: hsrc/hdst indexed by t (layer0), 0: single buffer
};

__launch_bounds__(512)
__global__ void recur_k(RecurArgs a) {
  __shared__ short wlds[32 * 1024];  // 64 KB swizzled weights (rows 0-15 phase1, 16-27 phase2, 28-31 zero)
  __shared__ float red[16 * 260];    // per-wave partial sums (padded rows)
  const int tid = threadIdx.x;
  const int bid = blockIdx.x;
  const int lane = tid & 63;
  const int wave = tid >> 6;
  const int j0 = bid * 4;
  const int l15 = lane & 15, l4 = lane >> 4;

  // ---- load + swizzle weights into LDS (bf16), rows: [g*4+jj]=Whh(g, j0+jj); 16+jj=pi; 20+jj=pf; 24+jj=po
  for (int ch = tid; ch < 28 * 128; ch += 512) {
    int row = ch >> 7, cc = ch & 127;
    int jj = row & 3;
    const float* src;
    if (row < 16)      src = a.Whh + (size_t)((row >> 2) * 1024 + j0 + jj) * 1024;
    else if (row < 20) src = a.Wpi + (size_t)(j0 + jj) * 1024;
    else if (row < 24) src = a.Wpf + (size_t)(j0 + jj) * 1024;
    else               src = a.Wpo + (size_t)(j0 + jj) * 1024;
    float4 f0 = *(const float4*)(src + cc * 8);
    float4 f1 = *(const float4*)(src + cc * 8 + 4);
    bf16x8 o;
    o[0] = f2bf(f0.x); o[1] = f2bf(f0.y); o[2] = f2bf(f0.z); o[3] = f2bf(f0.w);
    o[4] = f2bf(f1.x); o[5] = f2bf(f1.y); o[6] = f2bf(f1.z); o[7] = f2bf(f1.w);
    *(bf16x8*)(wlds + row * 1024 + (cc ^ (row & 7)) * 8) = o;
  }
  {
    int row = 28 + (tid >> 7), cc = tid & 127;
    bf16x8 z = 0;
    *(bf16x8*)(wlds + row * 1024 + cc * 8) = z;
  }
  __syncthreads();

  const bool owner = tid < 128;      // owner thread for (b=tid>>2, jj=tid&3)
  const int ob = tid >> 2, ojj = tid & 3;
  const int oj = j0 + ojj;
  const int lhi = ((ob & 15) >> 2) * 16;
  const int omt = ob >> 4, org = ob & 3;
  float c_reg = 0.f, pi_reg = 0.f, pf_reg = 0.f, opre_reg = 0.f;
  u32 epoch = 0;

  for (int t = 0; t < TT; ++t) {
    // -------- phase 1: gates = xg + Whh * h_{t-1}; c update --------
    if (t > 0) {
      const short* hb = a.hsrc + (a.h_seq ? (size_t)(t - 1) * BB * HH : 0);
      f32x4 acc0 = 0.f, acc1 = 0.f;
      for (int s = 0; s < 4; ++s) {
        int k = wave * 128 + s * 32 + l4 * 8;
        int cch = k >> 3;
        bf16x8 w8 = *(const bf16x8*)(wlds + l15 * 1024 + (cch ^ (l15 & 7)) * 8);
        bf16x8 h0 = *(const bf16x8*)(hb + (size_t)l15 * HH + k);
        bf16x8 h1 = *(const bf16x8*)(hb + (size_t)(16 + l15) * HH + k);
        acc0 = __builtin_amdgcn_mfma_f32_16x16x32_bf16(h0, w8, acc0, 0, 0, 0);
        acc1 = __builtin_amdgcn_mfma_f32_16x16x32_bf16(h1, w8, acc1, 0, 0, 0);
      }
      *(f32x4*)(red + (wave * 2 + 0) * 260 + lane * 4) = acc0;
      *(f32x4*)(red + (wave * 2 + 1) * 260 + lane * 4) = acc1;
    }
    __syncthreads();
    if (owner) {
      const short* xgp = a.xg + ((size_t)t * BB + ob) * 4096 + oj;
      float xi = bf2f(xgp[0]), xf = bf2f(xgp[1024]), xgv = bf2f(xgp[2048]), xo = bf2f(xgp[3072]);
      float gi = 0.f, gf = 0.f, gg = 0.f, go = 0.f;
      if (t > 0) {
        for (int w = 0; w < 8; ++w) {
          const float* rp = red + (w * 2 + omt) * 260 + org;
          gi += rp[(lhi + ojj) * 4];
          gf += rp[(lhi + 4 + ojj) * 4];
          gg += rp[(lhi + 8 + ojj) * 4];
          go += rp[(lhi + 12 + ojj) * 4];
        }
      }
      float iv = sigmoid_(gi + xi + pi_reg);
      float fv = sigmoid_(gf + xf + pf_reg);
      float gv = tanh_(gg + xgv);
      float cnew = fv * c_reg + iv * gv;
      opre_reg = go + xo;
      c_reg = cnew;
      a.cbf[ob * HH + oj] = f2bf(cnew);
    }
    gbar(a.flags, ++epoch);
    // -------- phase 2: pi/pf/po = Wp{i,f,o} * c_t; h update --------
    {
      f32x4 acc0 = 0.f, acc1 = 0.f;
      const int wrow = 16 + l15;
      for (int s = 0; s < 4; ++s) {
        int k = wave * 128 + s * 32 + l4 * 8;
        int cch = k >> 3;
        bf16x8 w8 = *(const bf16x8*)(wlds + wrow * 1024 + (cch ^ (wrow & 7)) * 8);
        bf16x8 c0 = *(const bf16x8*)(a.cbf + (size_t)l15 * HH + k);
        bf16x8 c1 = *(const bf16x8*)(a.cbf + (size_t)(16 + l15) * HH + k);
        acc0 = __builtin_amdgcn_mfma_f32_16x16x32_bf16(c0, w8, acc0, 0, 0, 0);
        acc1 = __builtin_amdgcn_mfma_f32_16x16x32_bf16(c1, w8, acc1, 0, 0, 0);
      }
      *(f32x4*)(red + (wave * 2 + 0) * 260 + lane * 4) = acc0;
      *(f32x4*)(red + (wave * 2 + 1) * 260 + lane * 4) = acc1;
    }
    __syncthreads();
    if (owner) {
      float pin = 0.f, pfn = 0.f, po = 0.f;
      for (int w = 0; w < 8; ++w) {
        const float* rp = red + (w * 2 + omt) * 260 + org;
        pin += rp[(lhi + ojj) * 4];
        pfn += rp[(lhi + 4 + ojj) * 4];
        po  += rp[(lhi + 8 + ojj) * 4];
      }
      float ov = opre_reg + po;          // NO sigmoid on o (per source)
      float hv = ov * tanh_(c_reg);
      pi_reg = pin; pf_reg = pfn;
      short hb16 = f2bf(hv);
      if (a.h_seq) a.hdst[(size_t)t * BB * HH + ob * HH + oj] = hb16;
      else         a.hdst[ob * HH + oj] = hb16;
      if (a.yout)  a.yout[(size_t)t * BB * HH + ob * HH + oj] = hv;
      if (t == TT - 1) { a.hn_out[ob * HH + oj] = hv; a.cn_out[ob * HH + oj] = c_reg; }
    }
    gbar(a.flags, ++epoch);
  }
}

extern "C" void kernel_launch(void* const* d_in, const int* in_sizes, int n_in,
                              void* d_out, int out_size, void* d_ws, size_t ws_size,
                              hipStream_t stream) {
  const float* x    = (const float*)d_in[0];
  const float* wih0 = (const float*)d_in[1];
  const float* whh0 = (const float*)d_in[2];
  const float* wpi0 = (const float*)d_in[3];
  const float* wpf0 = (const float*)d_in[4];
  const float* wpo0 = (const float*)d_in[5];
  const float* wih1 = (const float*)d_in[6];
  const float* whh1 = (const float*)d_in[7];
  const float* wpi1 = (const float*)d_in[8];
  const float* wpf1 = (const float*)d_in[9];
  const float* wpo1 = (const float*)d_in[10];

  float* out = (float*)d_out;
  float* y1 = out;
  float* hn = out + (size_t)TT * BB * HH;          // 16777216
  float* cn = hn + 2 * BB * HH;                    // +65536

  char* ws = (char*)d_ws;
  short* xg    = (short*)(ws);                     // 134217728 B : [16384][4096] bf16
  short* xbf   = (short*)(ws + 134217728ull);      //  33554432 B : x bf16
  short* y0bf  = (short*)(ws + 167772160ull);      //  33554432 B : y0 bf16 (layer0 h history)
  short* wib0  = (short*)(ws + 201326592ull);      //   8388608 B : W_ih0 bf16
  short* wib1  = (short*)(ws + 209715200ull);      //   8388608 B : W_ih1 bf16
  short* h1bf  = (short*)(ws + 218103808ull);      //     65536 B : layer1 h buffer
  short* cbf   = (short*)(ws + 218169344ull);      //     65536 B : c exchange
  u32*   flags = (u32*)  (ws + 218234880ull);      //      1024 B : barrier flags

  f32_to_bf16_k<<<8192, 256, 0, stream>>>(x, xbf, 16777216);
  f32_to_bf16_k<<<2048, 256, 0, stream>>>(wih0, wib0, 4194304);
  f32_to_bf16_k<<<2048, 256, 0, stream>>>(wih1, wib1, 4194304);

  dim3 gproj(128, 32, 1);
  gemm_bt_k<<<gproj, 256, 0, stream>>>(xbf, wib0, xg, 16384, 4096, 1024);

  hipMemsetAsync(flags, 0, 1024, stream);
  RecurArgs a0 = {whh0, wpi0, wpf0, wpo0, xg, y0bf, y0bf, nullptr, cbf, hn, cn, flags, 1};
  recur_k<<<256, 512, 0, stream>>>(a0);

  gemm_bt_k<<<gproj, 256, 0, stream>>>(y0bf, wib1, xg, 16384, 4096, 1024);

  hipMemsetAsync(flags, 0, 1024, stream);
  RecurArgs a1 = {whh1, wpi1, wpf1, wpo1, xg, h1bf, h1bf, y1, cbf, hn + BB * HH, cn + BB * HH, flags, 0};
  recur_k<<<256, 512, 0, stream>>>(a1);
}

// Round 5
// 19654.318 us; speedup vs baseline: 1.3728x; 1.3728x over previous
//
#include <hip/hip_runtime.h>
#include <stdint.h>

typedef __attribute__((ext_vector_type(8))) short bf16x8;
typedef __attribute__((ext_vector_type(4))) float f32x4;
typedef unsigned int u32;
typedef unsigned long long u64;

#define TT 512
#define BB 32
#define HH 1024

#define LD_AG(p)     __hip_atomic_load((p), __ATOMIC_RELAXED, __HIP_MEMORY_SCOPE_AGENT)
#define ST_AG(p, v)  __hip_atomic_store((p), (v), __ATOMIC_RELAXED, __HIP_MEMORY_SCOPE_AGENT)

__device__ __forceinline__ short f2bf(float f) {
  union { float f; u32 u; } v; v.f = f;
  u32 r = v.u + 0x7fffu + ((v.u >> 16) & 1u);
  return (short)(r >> 16);
}
__device__ __forceinline__ float bf2f(short s) {
  union { float f; u32 u; } v; v.u = ((u32)(unsigned short)s) << 16;
  return v.f;
}
__device__ __forceinline__ float sigmoid_(float x) { return 1.f / (1.f + __expf(-x)); }
__device__ __forceinline__ float tanh_(float x) {
  float cx = fminf(fmaxf(x, -15.f), 15.f);
  float e = __expf(2.f * cx);
  return (e - 1.f) / (e + 1.f);
}

union U64x2 { u64 q[2]; bf16x8 v; };
union U64s  { u64 q; short s[4]; };

// ---------------- fp32 -> bf16 convert ----------------
__global__ void f32_to_bf16_k(const float* __restrict__ in, short* __restrict__ out, int n) {
  int i = (blockIdx.x * blockDim.x + threadIdx.x) * 8;
  if (i + 8 > n) return;
  float4 a = *(const float4*)(in + i);
  float4 b = *(const float4*)(in + i + 4);
  bf16x8 o;
  o[0] = f2bf(a.x); o[1] = f2bf(a.y); o[2] = f2bf(a.z); o[3] = f2bf(a.w);
  o[4] = f2bf(b.x); o[5] = f2bf(b.y); o[6] = f2bf(b.z); o[7] = f2bf(b.w);
  *(bf16x8*)(out + i) = o;
}

// ------- proj GEMM: C[m][n] = sum_k A[m][k]*B[n][k]; bf16 in, bf16 out -------
__launch_bounds__(256)
__global__ void gemm_bt_k(const short* __restrict__ A, const short* __restrict__ B,
                          short* __restrict__ C, int M, int N, int K) {
  __shared__ short As[128 * 64];
  __shared__ short Bs[128 * 64];
  const int tid = threadIdx.x;
  const int lane = tid & 63;
  const int wave = tid >> 6;
  const int m0 = blockIdx.x * 128, n0 = blockIdx.y * 128;
  const int wm = (wave >> 1) * 64, wn = (wave & 1) * 64;
  f32x4 acc[4][4];
  for (int i = 0; i < 4; i++)
    for (int j = 0; j < 4; j++) acc[i][j] = 0.f;
  bf16x8* Asv = (bf16x8*)As;
  bf16x8* Bsv = (bf16x8*)Bs;
  for (int k0 = 0; k0 < K; k0 += 64) {
    __syncthreads();
    for (int q = 0; q < 4; ++q) {
      int chunk = tid + q * 256;
      int row = chunk >> 3, col = (chunk & 7) * 8;
      Asv[chunk] = *(const bf16x8*)(A + (size_t)(m0 + row) * K + k0 + col);
      Bsv[chunk] = *(const bf16x8*)(B + (size_t)(n0 + row) * K + k0 + col);
    }
    __syncthreads();
    for (int ks = 0; ks < 2; ++ks) {
      int kk = ks * 32 + (lane >> 4) * 8;
      bf16x8 af[4], bfr[4];
      for (int i = 0; i < 4; i++) af[i] = *(const bf16x8*)(As + (wm + i * 16 + (lane & 15)) * 64 + kk);
      for (int j = 0; j < 4; j++) bfr[j] = *(const bf16x8*)(Bs + (wn + j * 16 + (lane & 15)) * 64 + kk);
      for (int i = 0; i < 4; i++)
        for (int j = 0; j < 4; j++)
          acc[i][j] = __builtin_amdgcn_mfma_f32_16x16x32_bf16(af[i], bfr[j], acc[i][j], 0, 0, 0);
    }
  }
  const int r4 = (lane >> 4) * 4, nn = lane & 15;
  for (int i = 0; i < 4; i++)
    for (int j = 0; j < 4; j++) {
      int gm = m0 + wm + i * 16 + r4;
      int gn = n0 + wn + j * 16 + nn;
      for (int r = 0; r < 4; r++) C[(size_t)(gm + r) * N + gn] = f2bf(acc[i][j][r]);
    }
}

// ---- fence-free grid barrier: data already agent-coherent (sc-bit stores) ----
__device__ __forceinline__ void gbar(u32* flags, u32 epoch) {
  __syncthreads();
  if (threadIdx.x == 0) {
    asm volatile("s_waitcnt vmcnt(0)" ::: "memory");  // data stores at LLC before flag
    ST_AG(flags + blockIdx.x, epoch);
  }
  if (threadIdx.x < 64) {
    const int i0 = threadIdx.x * 4;
    for (;;) {
      u32 v0 = LD_AG(flags + i0 + 0);
      u32 v1 = LD_AG(flags + i0 + 1);
      u32 v2 = LD_AG(flags + i0 + 2);
      u32 v3 = LD_AG(flags + i0 + 3);
      int ok = (v0 >= epoch) & (v1 >= epoch) & (v2 >= epoch) & (v3 >= epoch);
      if (__all(ok)) break;
    }
  }
  __syncthreads();
}

// ---------------- persistent recurrent kernel (one layer) ----------------
struct RecurArgs {
  const float *Whh, *Wpi, *Wpf, *Wpo;
  const short* xg;    // [T*B][4096] bf16
  const short* hsrc;  // h read base (bf16, agent-coherent)
  short* hdst;        // h write base
  float* yout;        // layer1 fp32 y out, else null
  short* cbf;         // [B][H] c exchange
  float* hn_out;
  float* cn_out;
  u32* flags;
  int h_seq;          // 1: h indexed by t (layer0)
};

__launch_bounds__(512)
__global__ void recur_k(RecurArgs a) {
  __shared__ short wlds[32 * 1024];
  __shared__ float red[16 * 260];
  const int tid = threadIdx.x;
  const int bid = blockIdx.x;
  const int lane = tid & 63;
  const int wave = tid >> 6;
  const int j0 = bid * 4;
  const int l15 = lane & 15, l4 = lane >> 4;

  // weights -> LDS (bf16, swizzled): rows g*4+jj = Whh(g, j0+jj); 16+p*4+jj = peephole p
  for (int ch = tid; ch < 28 * 128; ch += 512) {
    int row = ch >> 7, cc = ch & 127;
    int jj = row & 3;
    const float* src;
    if (row < 16)      src = a.Whh + (size_t)((row >> 2) * 1024 + j0 + jj) * 1024;
    else if (row < 20) src = a.Wpi + (size_t)(j0 + jj) * 1024;
    else if (row < 24) src = a.Wpf + (size_t)(j0 + jj) * 1024;
    else               src = a.Wpo + (size_t)(j0 + jj) * 1024;
    float4 f0 = *(const float4*)(src + cc * 8);
    float4 f1 = *(const float4*)(src + cc * 8 + 4);
    bf16x8 o;
    o[0] = f2bf(f0.x); o[1] = f2bf(f0.y); o[2] = f2bf(f0.z); o[3] = f2bf(f0.w);
    o[4] = f2bf(f1.x); o[5] = f2bf(f1.y); o[6] = f2bf(f1.z); o[7] = f2bf(f1.w);
    *(bf16x8*)(wlds + row * 1024 + (cc ^ (row & 7)) * 8) = o;
  }
  {
    int row = 28 + (tid >> 7), cc = tid & 127;
    bf16x8 z = 0;
    *(bf16x8*)(wlds + row * 1024 + cc * 8) = z;
  }
  __syncthreads();

  // 32 owner threads: owner ob (=batch row) handles columns j0..j0+3
  const bool owner = tid < 32;
  const int ob = tid;
  const int omt = (ob >> 4) & 1;
  const int lhi = ((ob & 15) >> 2) * 16;
  const int org = ob & 3;
  float c_reg[4] = {0.f, 0.f, 0.f, 0.f};
  float pi_reg[4] = {0.f, 0.f, 0.f, 0.f};
  float pf_reg[4] = {0.f, 0.f, 0.f, 0.f};
  float opre_reg[4];
  u32 epoch = 0;

  for (int t = 0; t < TT; ++t) {
    // hoist owner xg loads (plain cached; latency overlaps MFMA below)
    U64s xq[4];
    if (owner) {
      const short* xgp = a.xg + ((size_t)t * BB + ob) * 4096 + j0;
      xq[0].q = *(const u64*)(xgp);
      xq[1].q = *(const u64*)(xgp + 1024);
      xq[2].q = *(const u64*)(xgp + 2048);
      xq[3].q = *(const u64*)(xgp + 3072);
    }
    // -------- phase 1: gates = xg + Whh * h_{t-1}; c update --------
    if (t > 0) {
      const short* hb = a.hsrc + (a.h_seq ? (size_t)(t - 1) * BB * HH : 0);
      f32x4 acc0 = 0.f, acc1 = 0.f;
      for (int s = 0; s < 4; ++s) {
        int k = wave * 128 + s * 32 + l4 * 8;
        int cch = k >> 3;
        bf16x8 w8 = *(const bf16x8*)(wlds + l15 * 1024 + (cch ^ (l15 & 7)) * 8);
        const u64* p0 = (const u64*)(hb + (size_t)l15 * HH + k);
        const u64* p1 = (const u64*)(hb + (size_t)(16 + l15) * HH + k);
        U64x2 h0, h1;
        h0.q[0] = LD_AG(p0); h0.q[1] = LD_AG(p0 + 1);
        h1.q[0] = LD_AG(p1); h1.q[1] = LD_AG(p1 + 1);
        acc0 = __builtin_amdgcn_mfma_f32_16x16x32_bf16(h0.v, w8, acc0, 0, 0, 0);
        acc1 = __builtin_amdgcn_mfma_f32_16x16x32_bf16(h1.v, w8, acc1, 0, 0, 0);
      }
      *(f32x4*)(red + (wave * 2 + 0) * 260 + lane * 4) = acc0;
      *(f32x4*)(red + (wave * 2 + 1) * 260 + lane * 4) = acc1;
    }
    __syncthreads();
    if (owner) {
      U64s cs;
      for (int jj = 0; jj < 4; ++jj) {
        float gi = 0.f, gf = 0.f, gg = 0.f, go = 0.f;
        if (t > 0) {
          for (int w = 0; w < 8; ++w) {
            const float* rp = red + (w * 2 + omt) * 260 + org;
            gi += rp[(lhi + jj) * 4];
            gf += rp[(lhi + 4 + jj) * 4];
            gg += rp[(lhi + 8 + jj) * 4];
            go += rp[(lhi + 12 + jj) * 4];
          }
        }
        float iv = sigmoid_(gi + bf2f(xq[0].s[jj]) + pi_reg[jj]);
        float fv = sigmoid_(gf + bf2f(xq[1].s[jj]) + pf_reg[jj]);
        float gv = tanh_(gg + bf2f(xq[2].s[jj]));
        float cnew = fv * c_reg[jj] + iv * gv;
        opre_reg[jj] = go + bf2f(xq[3].s[jj]);
        c_reg[jj] = cnew;
        cs.s[jj] = f2bf(cnew);
      }
      ST_AG((u64*)(a.cbf + ob * HH + j0), cs.q);
    }
    gbar(a.flags, ++epoch);
    // -------- phase 2: pi/pf/po = Wp{i,f,o} * c_t; h update --------
    {
      f32x4 acc0 = 0.f, acc1 = 0.f;
      const int wrow = 16 + l15;
      for (int s = 0; s < 4; ++s) {
        int k = wave * 128 + s * 32 + l4 * 8;
        int cch = k >> 3;
        bf16x8 w8 = *(const bf16x8*)(wlds + wrow * 1024 + (cch ^ (wrow & 7)) * 8);
        const u64* p0 = (const u64*)(a.cbf + (size_t)l15 * HH + k);
        const u64* p1 = (const u64*)(a.cbf + (size_t)(16 + l15) * HH + k);
        U64x2 c0, c1;
        c0.q[0] = LD_AG(p0); c0.q[1] = LD_AG(p0 + 1);
        c1.q[0] = LD_AG(p1); c1.q[1] = LD_AG(p1 + 1);
        acc0 = __builtin_amdgcn_mfma_f32_16x16x32_bf16(c0.v, w8, acc0, 0, 0, 0);
        acc1 = __builtin_amdgcn_mfma_f32_16x16x32_bf16(c1.v, w8, acc1, 0, 0, 0);
      }
      *(f32x4*)(red + (wave * 2 + 0) * 260 + lane * 4) = acc0;
      *(f32x4*)(red + (wave * 2 + 1) * 260 + lane * 4) = acc1;
    }
    __syncthreads();
    if (owner) {
      U64s hs;
      float hv4[4];
      for (int jj = 0; jj < 4; ++jj) {
        float pin = 0.f, pfn = 0.f, po = 0.f;
        for (int w = 0; w < 8; ++w) {
          const float* rp = red + (w * 2 + omt) * 260 + org;
          pin += rp[(lhi + jj) * 4];
          pfn += rp[(lhi + 4 + jj) * 4];
          po  += rp[(lhi + 8 + jj) * 4];
        }
        float ov = opre_reg[jj] + po;  // NO sigmoid on o (per source)
        float hv = ov * tanh_(c_reg[jj]);
        pi_reg[jj] = pin; pf_reg[jj] = pfn;
        hs.s[jj] = f2bf(hv);
        hv4[jj] = hv;
      }
      u64* hd = (u64*)(a.hdst + (a.h_seq ? (size_t)t * BB * HH : 0) + ob * HH + j0);
      ST_AG(hd, hs.q);
      if (a.yout) *(float4*)(a.yout + (size_t)t * BB * HH + ob * HH + j0) =
                      make_float4(hv4[0], hv4[1], hv4[2], hv4[3]);
      if (t == TT - 1) {
        *(float4*)(a.hn_out + ob * HH + j0) = make_float4(hv4[0], hv4[1], hv4[2], hv4[3]);
        *(float4*)(a.cn_out + ob * HH + j0) =
            make_float4(c_reg[0], c_reg[1], c_reg[2], c_reg[3]);
      }
    }
    gbar(a.flags, ++epoch);
  }
}

extern "C" void kernel_launch(void* const* d_in, const int* in_sizes, int n_in,
                              void* d_out, int out_size, void* d_ws, size_t ws_size,
                              hipStream_t stream) {
  const float* x    = (const float*)d_in[0];
  const float* wih0 = (const float*)d_in[1];
  const float* whh0 = (const float*)d_in[2];
  const float* wpi0 = (const float*)d_in[3];
  const float* wpf0 = (const float*)d_in[4];
  const float* wpo0 = (const float*)d_in[5];
  const float* wih1 = (const float*)d_in[6];
  const float* whh1 = (const float*)d_in[7];
  const float* wpi1 = (const float*)d_in[8];
  const float* wpf1 = (const float*)d_in[9];
  const float* wpo1 = (const float*)d_in[10];

  float* out = (float*)d_out;
  float* y1 = out;
  float* hn = out + (size_t)TT * BB * HH;
  float* cn = hn + 2 * BB * HH;

  char* ws = (char*)d_ws;
  short* xg    = (short*)(ws);                     // 134217728 B
  short* xbf   = (short*)(ws + 134217728ull);      //  33554432 B
  short* y0bf  = (short*)(ws + 167772160ull);      //  33554432 B
  short* wib0  = (short*)(ws + 201326592ull);      //   8388608 B
  short* wib1  = (short*)(ws + 209715200ull);      //   8388608 B
  short* h1bf  = (short*)(ws + 218103808ull);      //     65536 B
  short* cbf   = (short*)(ws + 218169344ull);      //     65536 B
  u32*   flags = (u32*)  (ws + 218234880ull);      //      1024 B

  f32_to_bf16_k<<<8192, 256, 0, stream>>>(x, xbf, 16777216);
  f32_to_bf16_k<<<2048, 256, 0, stream>>>(wih0, wib0, 4194304);
  f32_to_bf16_k<<<2048, 256, 0, stream>>>(wih1, wib1, 4194304);

  dim3 gproj(128, 32, 1);
  gemm_bt_k<<<gproj, 256, 0, stream>>>(xbf, wib0, xg, 16384, 4096, 1024);

  hipMemsetAsync(flags, 0, 1024, stream);
  RecurArgs a0 = {whh0, wpi0, wpf0, wpo0, xg, y0bf, y0bf, nullptr, cbf, hn, cn, flags, 1};
  recur_k<<<256, 512, 0, stream>>>(a0);

  gemm_bt_k<<<gproj, 256, 0, stream>>>(y0bf, wib1, xg, 16384, 4096, 1024);

  hipMemsetAsync(flags, 0, 1024, stream);
  RecurArgs a1 = {whh1, wpi1, wpf1, wpo1, xg, h1bf, h1bf, y1, cbf, hn + BB * HH, cn + BB * HH, flags, 0};
  recur_k<<<256, 512, 0, stream>>>(a1);
}

// Round 6
// 15801.529 us; speedup vs baseline: 1.7075x; 1.2438x over previous
//
#include <hip/hip_runtime.h>
#include <stdint.h>

typedef __attribute__((ext_vector_type(8))) short bf16x8;
typedef __attribute__((ext_vector_type(4))) float f32x4;
typedef unsigned int u32;
typedef unsigned long long u64;

#define TT 512
#define BB 32
#define HH 1024

#define LD_AG(p)     __hip_atomic_load((p), __ATOMIC_RELAXED, __HIP_MEMORY_SCOPE_AGENT)
#define ST_AG(p, v)  __hip_atomic_store((p), (v), __ATOMIC_RELAXED, __HIP_MEMORY_SCOPE_AGENT)

__device__ __forceinline__ short f2bf(float f) {
  union { float f; u32 u; } v; v.f = f;
  u32 r = v.u + 0x7fffu + ((v.u >> 16) & 1u);
  return (short)(r >> 16);
}
__device__ __forceinline__ float bf2f(short s) {
  union { float f; u32 u; } v; v.u = ((u32)(unsigned short)s) << 16;
  return v.f;
}
__device__ __forceinline__ float sigmoid_(float x) { return 1.f / (1.f + __expf(-x)); }
__device__ __forceinline__ float tanh_(float x) {
  float cx = fminf(fmaxf(x, -15.f), 15.f);
  float e = __expf(2.f * cx);
  return (e - 1.f) / (e + 1.f);
}

union U64x2 { u64 q[2]; bf16x8 v; };
union U64s  { u64 q; short s[4]; };

// ---------------- fp32 -> bf16 convert ----------------
__global__ void f32_to_bf16_k(const float* __restrict__ in, short* __restrict__ out, int n) {
  int i = (blockIdx.x * blockDim.x + threadIdx.x) * 8;
  if (i + 8 > n) return;
  float4 a = *(const float4*)(in + i);
  float4 b = *(const float4*)(in + i + 4);
  bf16x8 o;
  o[0] = f2bf(a.x); o[1] = f2bf(a.y); o[2] = f2bf(a.z); o[3] = f2bf(a.w);
  o[4] = f2bf(b.x); o[5] = f2bf(b.y); o[6] = f2bf(b.z); o[7] = f2bf(b.w);
  *(bf16x8*)(out + i) = o;
}

// ------- proj GEMM: C[m][n] = sum_k A[m][k]*B[n][k]; bf16 in, bf16 out -------
__launch_bounds__(256)
__global__ void gemm_bt_k(const short* __restrict__ A, const short* __restrict__ B,
                          short* __restrict__ C, int M, int N, int K) {
  __shared__ short As[128 * 64];
  __shared__ short Bs[128 * 64];
  const int tid = threadIdx.x;
  const int lane = tid & 63;
  const int wave = tid >> 6;
  const int m0 = blockIdx.x * 128, n0 = blockIdx.y * 128;
  const int wm = (wave >> 1) * 64, wn = (wave & 1) * 64;
  f32x4 acc[4][4];
  for (int i = 0; i < 4; i++)
    for (int j = 0; j < 4; j++) acc[i][j] = 0.f;
  bf16x8* Asv = (bf16x8*)As;
  bf16x8* Bsv = (bf16x8*)Bs;
  for (int k0 = 0; k0 < K; k0 += 64) {
    __syncthreads();
    for (int q = 0; q < 4; ++q) {
      int chunk = tid + q * 256;
      int row = chunk >> 3, col = (chunk & 7) * 8;
      Asv[chunk] = *(const bf16x8*)(A + (size_t)(m0 + row) * K + k0 + col);
      Bsv[chunk] = *(const bf16x8*)(B + (size_t)(n0 + row) * K + k0 + col);
    }
    __syncthreads();
    for (int ks = 0; ks < 2; ++ks) {
      int kk = ks * 32 + (lane >> 4) * 8;
      bf16x8 af[4], bfr[4];
      for (int i = 0; i < 4; i++) af[i] = *(const bf16x8*)(As + (wm + i * 16 + (lane & 15)) * 64 + kk);
      for (int j = 0; j < 4; j++) bfr[j] = *(const bf16x8*)(Bs + (wn + j * 16 + (lane & 15)) * 64 + kk);
      for (int i = 0; i < 4; i++)
        for (int j = 0; j < 4; j++)
          acc[i][j] = __builtin_amdgcn_mfma_f32_16x16x32_bf16(af[i], bfr[j], acc[i][j], 0, 0, 0);
    }
  }
  const int r4 = (lane >> 4) * 4, nn = lane & 15;
  for (int i = 0; i < 4; i++)
    for (int j = 0; j < 4; j++) {
      int gm = m0 + wm + i * 16 + r4;
      int gn = n0 + wn + j * 16 + nn;
      for (int r = 0; r < 4; r++) C[(size_t)(gm + r) * N + gn] = f2bf(acc[i][j][r]);
    }
}

// ---- counter-based grid barrier: 8 spread counters, low LLC poll traffic ----
// ctr: 8 u32 counters spaced 256 B (64 u32) apart. Each block adds 1 to
// counter (bid&7); pollers read 8 words/iter. target = epoch * (grid/8).
__device__ __forceinline__ void gbar(u32* ctr, u32 target) {
  __syncthreads();
  if (threadIdx.x == 0) {
    asm volatile("s_waitcnt vmcnt(0)" ::: "memory");  // data stores at LLC before arrival
    __hip_atomic_fetch_add(ctr + (blockIdx.x & 7) * 64, 1u,
                           __ATOMIC_RELAXED, __HIP_MEMORY_SCOPE_AGENT);
  }
  if (threadIdx.x < 64) {
    const int lane = threadIdx.x;
    for (;;) {
      u32 v = (lane < 8) ? LD_AG(ctr + lane * 64) : 0xffffffffu;
      if (__all(v >= target)) break;
    }
  }
  __syncthreads();
}

// ---------------- persistent recurrent kernel (one layer) ----------------
struct RecurArgs {
  const float *Whh, *Wpi, *Wpf, *Wpo;
  const short* xg;    // [T*B][4096] bf16
  const short* hsrc;  // h read base (bf16, agent-coherent)
  short* hdst;        // h write base
  float* yout;        // layer1 fp32 y out, else null
  short* cbf;         // [B][H] c exchange
  float* hn_out;
  float* cn_out;
  u32* ctr;           // barrier counters (8 x u32, 256B apart; pre-zeroed)
  int h_seq;          // 1: h indexed by t (layer0)
};

__launch_bounds__(512)
__global__ void recur_k(RecurArgs a) {
  __shared__ short wlds[32 * 1024];
  __shared__ float red[16 * 260];
  const int tid = threadIdx.x;
  const int bid = blockIdx.x;
  const int lane = tid & 63;
  const int wave = tid >> 6;
  const int j0 = bid * 4;
  const int l15 = lane & 15, l4 = lane >> 4;

  // weights -> LDS (bf16, swizzled): rows g*4+jj = Whh(g, j0+jj); 16+p*4+jj = peephole p
  for (int ch = tid; ch < 28 * 128; ch += 512) {
    int row = ch >> 7, cc = ch & 127;
    int jj = row & 3;
    const float* src;
    if (row < 16)      src = a.Whh + (size_t)((row >> 2) * 1024 + j0 + jj) * 1024;
    else if (row < 20) src = a.Wpi + (size_t)(j0 + jj) * 1024;
    else if (row < 24) src = a.Wpf + (size_t)(j0 + jj) * 1024;
    else               src = a.Wpo + (size_t)(j0 + jj) * 1024;
    float4 f0 = *(const float4*)(src + cc * 8);
    float4 f1 = *(const float4*)(src + cc * 8 + 4);
    bf16x8 o;
    o[0] = f2bf(f0.x); o[1] = f2bf(f0.y); o[2] = f2bf(f0.z); o[3] = f2bf(f0.w);
    o[4] = f2bf(f1.x); o[5] = f2bf(f1.y); o[6] = f2bf(f1.z); o[7] = f2bf(f1.w);
    *(bf16x8*)(wlds + row * 1024 + (cc ^ (row & 7)) * 8) = o;
  }
  {
    int row = 28 + (tid >> 7), cc = tid & 127;
    bf16x8 z = 0;
    *(bf16x8*)(wlds + row * 1024 + cc * 8) = z;
  }
  __syncthreads();

  // 32 owner threads: owner ob (=batch row) handles columns j0..j0+3
  const bool owner = tid < 32;
  const int ob = tid;
  const int omt = (ob >> 4) & 1;
  const int lhi = ((ob & 15) >> 2) * 16;
  const int org = ob & 3;
  float c_reg[4] = {0.f, 0.f, 0.f, 0.f};
  float pi_reg[4] = {0.f, 0.f, 0.f, 0.f};
  float pf_reg[4] = {0.f, 0.f, 0.f, 0.f};
  float opre_reg[4];
  u32 epoch = 0;

  for (int t = 0; t < TT; ++t) {
    // hoist owner xg loads (plain cached; latency overlaps MFMA below)
    U64s xq[4];
    if (owner) {
      const short* xgp = a.xg + ((size_t)t * BB + ob) * 4096 + j0;
      xq[0].q = *(const u64*)(xgp);
      xq[1].q = *(const u64*)(xgp + 1024);
      xq[2].q = *(const u64*)(xgp + 2048);
      xq[3].q = *(const u64*)(xgp + 3072);
    }
    // -------- phase 1: gates = xg + Whh * h_{t-1}; c update --------
    if (t > 0) {
      const short* hb = a.hsrc + (a.h_seq ? (size_t)(t - 1) * BB * HH : 0);
      f32x4 acc0 = 0.f, acc1 = 0.f;
      for (int s = 0; s < 4; ++s) {
        int k = wave * 128 + s * 32 + l4 * 8;
        int cch = k >> 3;
        bf16x8 w8 = *(const bf16x8*)(wlds + l15 * 1024 + (cch ^ (l15 & 7)) * 8);
        const u64* p0 = (const u64*)(hb + (size_t)l15 * HH + k);
        const u64* p1 = (const u64*)(hb + (size_t)(16 + l15) * HH + k);
        U64x2 h0, h1;
        h0.q[0] = LD_AG(p0); h0.q[1] = LD_AG(p0 + 1);
        h1.q[0] = LD_AG(p1); h1.q[1] = LD_AG(p1 + 1);
        acc0 = __builtin_amdgcn_mfma_f32_16x16x32_bf16(h0.v, w8, acc0, 0, 0, 0);
        acc1 = __builtin_amdgcn_mfma_f32_16x16x32_bf16(h1.v, w8, acc1, 0, 0, 0);
      }
      *(f32x4*)(red + (wave * 2 + 0) * 260 + lane * 4) = acc0;
      *(f32x4*)(red + (wave * 2 + 1) * 260 + lane * 4) = acc1;
    }
    __syncthreads();
    if (owner) {
      U64s cs;
      for (int jj = 0; jj < 4; ++jj) {
        float gi = 0.f, gf = 0.f, gg = 0.f, go = 0.f;
        if (t > 0) {
          for (int w = 0; w < 8; ++w) {
            const float* rp = red + (w * 2 + omt) * 260 + org;
            gi += rp[(lhi + jj) * 4];
            gf += rp[(lhi + 4 + jj) * 4];
            gg += rp[(lhi + 8 + jj) * 4];
            go += rp[(lhi + 12 + jj) * 4];
          }
        }
        float iv = sigmoid_(gi + bf2f(xq[0].s[jj]) + pi_reg[jj]);
        float fv = sigmoid_(gf + bf2f(xq[1].s[jj]) + pf_reg[jj]);
        float gv = tanh_(gg + bf2f(xq[2].s[jj]));
        float cnew = fv * c_reg[jj] + iv * gv;
        opre_reg[jj] = go + bf2f(xq[3].s[jj]);
        c_reg[jj] = cnew;
        cs.s[jj] = f2bf(cnew);
      }
      ST_AG((u64*)(a.cbf + ob * HH + j0), cs.q);
    }
    gbar(a.ctr, (++epoch) * 32);
    // -------- phase 2: pi/pf/po = Wp{i,f,o} * c_t; h update --------
    {
      f32x4 acc0 = 0.f, acc1 = 0.f;
      const int wrow = 16 + l15;
      for (int s = 0; s < 4; ++s) {
        int k = wave * 128 + s * 32 + l4 * 8;
        int cch = k >> 3;
        bf16x8 w8 = *(const bf16x8*)(wlds + wrow * 1024 + (cch ^ (wrow & 7)) * 8);
        const u64* p0 = (const u64*)(a.cbf + (size_t)l15 * HH + k);
        const u64* p1 = (const u64*)(a.cbf + (size_t)(16 + l15) * HH + k);
        U64x2 c0, c1;
        c0.q[0] = LD_AG(p0); c0.q[1] = LD_AG(p0 + 1);
        c1.q[0] = LD_AG(p1); c1.q[1] = LD_AG(p1 + 1);
        acc0 = __builtin_amdgcn_mfma_f32_16x16x32_bf16(c0.v, w8, acc0, 0, 0, 0);
        acc1 = __builtin_amdgcn_mfma_f32_16x16x32_bf16(c1.v, w8, acc1, 0, 0, 0);
      }
      *(f32x4*)(red + (wave * 2 + 0) * 260 + lane * 4) = acc0;
      *(f32x4*)(red + (wave * 2 + 1) * 260 + lane * 4) = acc1;
    }
    __syncthreads();
    if (owner) {
      U64s hs;
      float hv4[4];
      for (int jj = 0; jj < 4; ++jj) {
        float pin = 0.f, pfn = 0.f, po = 0.f;
        for (int w = 0; w < 8; ++w) {
          const float* rp = red + (w * 2 + omt) * 260 + org;
          pin += rp[(lhi + jj) * 4];
          pfn += rp[(lhi + 4 + jj) * 4];
          po  += rp[(lhi + 8 + jj) * 4];
        }
        float ov = opre_reg[jj] + po;  // NO sigmoid on o (per source)
        float hv = ov * tanh_(c_reg[jj]);
        pi_reg[jj] = pin; pf_reg[jj] = pfn;
        hs.s[jj] = f2bf(hv);
        hv4[jj] = hv;
      }
      u64* hd = (u64*)(a.hdst + (a.h_seq ? (size_t)t * BB * HH : 0) + ob * HH + j0);
      ST_AG(hd, hs.q);
      if (a.yout) *(float4*)(a.yout + (size_t)t * BB * HH + ob * HH + j0) =
                      make_float4(hv4[0], hv4[1], hv4[2], hv4[3]);
      if (t == TT - 1) {
        *(float4*)(a.hn_out + ob * HH + j0) = make_float4(hv4[0], hv4[1], hv4[2], hv4[3]);
        *(float4*)(a.cn_out + ob * HH + j0) =
            make_float4(c_reg[0], c_reg[1], c_reg[2], c_reg[3]);
      }
    }
    gbar(a.ctr, (++epoch) * 32);
  }
}

extern "C" void kernel_launch(void* const* d_in, const int* in_sizes, int n_in,
                              void* d_out, int out_size, void* d_ws, size_t ws_size,
                              hipStream_t stream) {
  const float* x    = (const float*)d_in[0];
  const float* wih0 = (const float*)d_in[1];
  const float* whh0 = (const float*)d_in[2];
  const float* wpi0 = (const float*)d_in[3];
  const float* wpf0 = (const float*)d_in[4];
  const float* wpo0 = (const float*)d_in[5];
  const float* wih1 = (const float*)d_in[6];
  const float* whh1 = (const float*)d_in[7];
  const float* wpi1 = (const float*)d_in[8];
  const float* wpf1 = (const float*)d_in[9];
  const float* wpo1 = (const float*)d_in[10];

  float* out = (float*)d_out;
  float* y1 = out;
  float* hn = out + (size_t)TT * BB * HH;
  float* cn = hn + 2 * BB * HH;

  char* ws = (char*)d_ws;
  short* xg    = (short*)(ws);                     // 134217728 B
  short* xbf   = (short*)(ws + 134217728ull);      //  33554432 B
  short* y0bf  = (short*)(ws + 167772160ull);      //  33554432 B
  short* wib0  = (short*)(ws + 201326592ull);      //   8388608 B
  short* wib1  = (short*)(ws + 209715200ull);      //   8388608 B
  short* h1bf  = (short*)(ws + 218103808ull);      //     65536 B
  short* cbf   = (short*)(ws + 218169344ull);      //     65536 B
  u32*   ctr   = (u32*)  (ws + 218234880ull);      //      2048 B : 8 counters, 256B apart

  f32_to_bf16_k<<<8192, 256, 0, stream>>>(x, xbf, 16777216);
  f32_to_bf16_k<<<2048, 256, 0, stream>>>(wih0, wib0, 4194304);
  f32_to_bf16_k<<<2048, 256, 0, stream>>>(wih1, wib1, 4194304);

  dim3 gproj(128, 32, 1);
  gemm_bt_k<<<gproj, 256, 0, stream>>>(xbf, wib0, xg, 16384, 4096, 1024);

  hipMemsetAsync(ctr, 0, 2048, stream);
  RecurArgs a0 = {whh0, wpi0, wpf0, wpo0, xg, y0bf, y0bf, nullptr, cbf, hn, cn, ctr, 1};
  recur_k<<<256, 512, 0, stream>>>(a0);

  gemm_bt_k<<<gproj, 256, 0, stream>>>(y0bf, wib1, xg, 16384, 4096, 1024);

  hipMemsetAsync(ctr, 0, 2048, stream);
  RecurArgs a1 = {whh1, wpi1, wpf1, wpo1, xg, h1bf, h1bf, y1, cbf, hn + BB * HH, cn + BB * HH, ctr, 0};
  recur_k<<<256, 512, 0, stream>>>(a1);
}

// Round 8
// 12592.606 us; speedup vs baseline: 2.1426x; 1.2548x over previous
//
#include <hip/hip_runtime.h>
#include <stdint.h>

typedef __attribute__((ext_vector_type(8))) short bf16x8;
typedef __attribute__((ext_vector_type(4))) float f32x4;
typedef unsigned int u32;
typedef unsigned long long u64;

#define TT 512
#define BB 32
#define HH 1024

#define LD_AG(p)     __hip_atomic_load((p), __ATOMIC_RELAXED, __HIP_MEMORY_SCOPE_AGENT)
#define ST_AG(p, v)  __hip_atomic_store((p), (v), __ATOMIC_RELAXED, __HIP_MEMORY_SCOPE_AGENT)
// 16B L2-bypassing load, issued WITHOUT waitcnt (caller waits via vmcnt(0)+sched_barrier)
#define GLD16(dst, ptr) \
  asm volatile("global_load_dwordx4 %0, %1, off sc0 sc1" : "=v"(dst) : "v"(ptr))

__device__ __forceinline__ short f2bf(float f) {
  union { float f; u32 u; } v; v.f = f;
  u32 r = v.u + 0x7fffu + ((v.u >> 16) & 1u);
  return (short)(r >> 16);
}
__device__ __forceinline__ float bf2f(short s) {
  union { float f; u32 u; } v; v.u = ((u32)(unsigned short)s) << 16;
  return v.f;
}
__device__ __forceinline__ float sigmoid_(float x) { return 1.f / (1.f + __expf(-x)); }
__device__ __forceinline__ float tanh_(float x) {
  float cx = fminf(fmaxf(x, -15.f), 15.f);
  float e = __expf(2.f * cx);
  return (e - 1.f) / (e + 1.f);
}

union U64s { u64 q; short s[4]; };

// ---------------- fp32 -> bf16 convert ----------------
__global__ void f32_to_bf16_k(const float* __restrict__ in, short* __restrict__ out, int n) {
  int i = (blockIdx.x * blockDim.x + threadIdx.x) * 8;
  if (i + 8 > n) return;
  float4 a = *(const float4*)(in + i);
  float4 b = *(const float4*)(in + i + 4);
  bf16x8 o;
  o[0] = f2bf(a.x); o[1] = f2bf(a.y); o[2] = f2bf(a.z); o[3] = f2bf(a.w);
  o[4] = f2bf(b.x); o[5] = f2bf(b.y); o[6] = f2bf(b.z); o[7] = f2bf(b.w);
  *(bf16x8*)(out + i) = o;
}

// ------- proj GEMM: C = A * B^T, epilogue scatters into recur-block-major xg --------
// out layout: xg[((t*256 + (col>>2))*32 + b)*16 + gate*4 + (col&3)]
__launch_bounds__(256)
__global__ void gemm_bt_k(const short* __restrict__ A, const short* __restrict__ B,
                          short* __restrict__ C, int M, int N, int K) {
  __shared__ short As[128 * 64];
  __shared__ short Bs[128 * 64];
  const int tid = threadIdx.x;
  const int lane = tid & 63;
  const int wave = tid >> 6;
  const int m0 = blockIdx.x * 128, n0 = blockIdx.y * 128;
  const int wm = (wave >> 1) * 64, wn = (wave & 1) * 64;
  f32x4 acc[4][4];
  for (int i = 0; i < 4; i++)
    for (int j = 0; j < 4; j++) acc[i][j] = 0.f;
  bf16x8* Asv = (bf16x8*)As;
  bf16x8* Bsv = (bf16x8*)Bs;
  for (int k0 = 0; k0 < K; k0 += 64) {
    __syncthreads();
    for (int q = 0; q < 4; ++q) {
      int chunk = tid + q * 256;
      int row = chunk >> 3, col = (chunk & 7) * 8;
      Asv[chunk] = *(const bf16x8*)(A + (size_t)(m0 + row) * K + k0 + col);
      Bsv[chunk] = *(const bf16x8*)(B + (size_t)(n0 + row) * K + k0 + col);
    }
    __syncthreads();
    for (int ks = 0; ks < 2; ++ks) {
      int kk = ks * 32 + (lane >> 4) * 8;
      bf16x8 af[4], bfr[4];
      for (int i = 0; i < 4; i++) af[i] = *(const bf16x8*)(As + (wm + i * 16 + (lane & 15)) * 64 + kk);
      for (int j = 0; j < 4; j++) bfr[j] = *(const bf16x8*)(Bs + (wn + j * 16 + (lane & 15)) * 64 + kk);
      for (int i = 0; i < 4; i++)
        for (int j = 0; j < 4; j++)
          acc[i][j] = __builtin_amdgcn_mfma_f32_16x16x32_bf16(af[i], bfr[j], acc[i][j], 0, 0, 0);
    }
  }
  const int r4 = (lane >> 4) * 4, nn = lane & 15;
  for (int i = 0; i < 4; i++)
    for (int j = 0; j < 4; j++) {
      for (int r = 0; r < 4; r++) {
        int gm = m0 + wm + i * 16 + r4 + r;       // = t*32 + b
        int gn = n0 + wn + j * 16 + nn;           // = gate*1024 + col
        int tt = gm >> 5, b = gm & 31;
        int g = gn >> 10, col = gn & 1023;
        size_t dst = (((size_t)tt * 256 + (col >> 2)) * 32 + b) * 16 + g * 4 + (col & 3);
        C[dst] = f2bf(acc[i][j][r]);
      }
    }
}

// ---- counter-based grid barrier: 8 spread counters, low LLC poll traffic ----
__device__ __forceinline__ void gbar(u32* ctr, u32 target) {
  __syncthreads();
  if (threadIdx.x == 0) {
    asm volatile("s_waitcnt vmcnt(0)" ::: "memory");  // data stores at LLC before arrival
    __hip_atomic_fetch_add(ctr + (blockIdx.x & 7) * 64, 1u,
                           __ATOMIC_RELAXED, __HIP_MEMORY_SCOPE_AGENT);
  }
  if (threadIdx.x < 64) {
    const int lane = threadIdx.x;
    for (;;) {
      u32 v = (lane < 8) ? LD_AG(ctr + lane * 64) : 0xffffffffu;
      if (__all(v >= target)) break;
    }
  }
  __syncthreads();
}

// ---------------- persistent recurrent kernel (one layer) ----------------
struct RecurArgs {
  const float *Whh, *Wpi, *Wpf, *Wpo;
  const short* xg;    // [T][256][32][16] bf16 block-major input proj
  const short* hsrc;  // h read base (bf16, agent-coherent)
  short* hdst;        // h write base
  float* yout;        // layer1 fp32 y out, else null
  short* cbf;         // [B][H] c exchange
  float* hn_out;
  float* cn_out;
  u32* ctr;           // barrier counters (8 x u32, 256B apart; pre-zeroed)
  int h_seq;          // 1: h indexed by t (layer0)
};

__launch_bounds__(512)
__global__ void recur_k(RecurArgs a) {
  __shared__ short wlds[32 * 1024];
  __shared__ float red[16 * 260];
  const int tid = threadIdx.x;
  const int bid = blockIdx.x;
  const int lane = tid & 63;
  const int wave = tid >> 6;
  const int j0 = bid * 4;
  const int l15 = lane & 15, l4 = lane >> 4;

  // weights -> LDS (bf16, swizzled): rows g*4+jj = Whh(g, j0+jj); 16+p*4+jj = peephole p
  for (int ch = tid; ch < 28 * 128; ch += 512) {
    int row = ch >> 7, cc = ch & 127;
    int jj = row & 3;
    const float* src;
    if (row < 16)      src = a.Whh + (size_t)((row >> 2) * 1024 + j0 + jj) * 1024;
    else if (row < 20) src = a.Wpi + (size_t)(j0 + jj) * 1024;
    else if (row < 24) src = a.Wpf + (size_t)(j0 + jj) * 1024;
    else               src = a.Wpo + (size_t)(j0 + jj) * 1024;
    float4 f0 = *(const float4*)(src + cc * 8);
    float4 f1 = *(const float4*)(src + cc * 8 + 4);
    bf16x8 o;
    o[0] = f2bf(f0.x); o[1] = f2bf(f0.y); o[2] = f2bf(f0.z); o[3] = f2bf(f0.w);
    o[4] = f2bf(f1.x); o[5] = f2bf(f1.y); o[6] = f2bf(f1.z); o[7] = f2bf(f1.w);
    *(bf16x8*)(wlds + row * 1024 + (cc ^ (row & 7)) * 8) = o;
  }
  {
    int row = 28 + (tid >> 7), cc = tid & 127;
    bf16x8 z = 0;
    *(bf16x8*)(wlds + row * 1024 + cc * 8) = z;
  }
  __syncthreads();

  // 32 owner threads: owner ob (=batch row) handles columns j0..j0+3
  const bool owner = tid < 32;
  const int ob = tid;
  const int omt = (ob >> 4) & 1;
  const int lhi = ((ob & 15) >> 2) * 16;
  const int org = ob & 3;
  float c_reg[4] = {0.f, 0.f, 0.f, 0.f};
  float pi_reg[4] = {0.f, 0.f, 0.f, 0.f};
  float pf_reg[4] = {0.f, 0.f, 0.f, 0.f};
  float opre_reg[4];
  u32 epoch = 0;

  for (int t = 0; t < TT; ++t) {
    // owner xg loads: one contiguous 32B chunk per owner (cached; block-private lines)
    bf16x8 xv0, xv1;
    if (owner) {
      const short* xgp = a.xg + (((size_t)t * 256 + bid) * 32 + ob) * 16;
      xv0 = *(const bf16x8*)(xgp);      // gates i,f  (jj 0..3 each)
      xv1 = *(const bf16x8*)(xgp + 8);  // gates g,o
    }
    // -------- phase 1: gates = xg + Whh * h_{t-1}; c update --------
    if (t > 0) {
      const short* hb = a.hsrc + (a.h_seq ? (size_t)(t - 1) * BB * HH : 0);
      bf16x8 h0[4], h1[4], w8[4];
#pragma unroll
      for (int s = 0; s < 4; ++s) {
        int k = wave * 128 + s * 32 + l4 * 8;
        GLD16(h0[s], hb + (size_t)l15 * HH + k);
        GLD16(h1[s], hb + (size_t)(16 + l15) * HH + k);
      }
#pragma unroll
      for (int s = 0; s < 4; ++s) {
        int k = wave * 128 + s * 32 + l4 * 8;
        int cch = k >> 3;
        w8[s] = *(const bf16x8*)(wlds + l15 * 1024 + (cch ^ (l15 & 7)) * 8);
      }
      asm volatile("s_waitcnt vmcnt(0)" ::: "memory");
      __builtin_amdgcn_sched_barrier(0);
      f32x4 acc0 = 0.f, acc1 = 0.f;
#pragma unroll
      for (int s = 0; s < 4; ++s) {
        acc0 = __builtin_amdgcn_mfma_f32_16x16x32_bf16(h0[s], w8[s], acc0, 0, 0, 0);
        acc1 = __builtin_amdgcn_mfma_f32_16x16x32_bf16(h1[s], w8[s], acc1, 0, 0, 0);
      }
      *(f32x4*)(red + (wave * 2 + 0) * 260 + lane * 4) = acc0;
      *(f32x4*)(red + (wave * 2 + 1) * 260 + lane * 4) = acc1;
    }
    __syncthreads();
    if (owner) {
      U64s cs;
      for (int jj = 0; jj < 4; ++jj) {
        float gi = 0.f, gf = 0.f, gg = 0.f, go = 0.f;
        if (t > 0) {
          for (int w = 0; w < 8; ++w) {
            const float* rp = red + (w * 2 + omt) * 260 + org;
            gi += rp[(lhi + jj) * 4];
            gf += rp[(lhi + 4 + jj) * 4];
            gg += rp[(lhi + 8 + jj) * 4];
            go += rp[(lhi + 12 + jj) * 4];
          }
        }
        float iv = sigmoid_(gi + bf2f(xv0[jj]) + pi_reg[jj]);
        float fv = sigmoid_(gf + bf2f(xv0[4 + jj]) + pf_reg[jj]);
        float gv = tanh_(gg + bf2f(xv1[jj]));
        float cnew = fv * c_reg[jj] + iv * gv;
        opre_reg[jj] = go + bf2f(xv1[4 + jj]);
        c_reg[jj] = cnew;
        cs.s[jj] = f2bf(cnew);
      }
      ST_AG((u64*)(a.cbf + ob * HH + j0), cs.q);
    }
    gbar(a.ctr, (++epoch) * 32);
    // -------- phase 2: pi/pf/po = Wp{i,f,o} * c_t; h update --------
    {
      bf16x8 c0[4], c1[4], w8[4];
      const int wrow = 16 + l15;
#pragma unroll
      for (int s = 0; s < 4; ++s) {
        int k = wave * 128 + s * 32 + l4 * 8;
        GLD16(c0[s], a.cbf + (size_t)l15 * HH + k);
        GLD16(c1[s], a.cbf + (size_t)(16 + l15) * HH + k);
      }
#pragma unroll
      for (int s = 0; s < 4; ++s) {
        int k = wave * 128 + s * 32 + l4 * 8;
        int cch = k >> 3;
        w8[s] = *(const bf16x8*)(wlds + wrow * 1024 + (cch ^ (wrow & 7)) * 8);
      }
      asm volatile("s_waitcnt vmcnt(0)" ::: "memory");
      __builtin_amdgcn_sched_barrier(0);
      f32x4 acc0 = 0.f, acc1 = 0.f;
#pragma unroll
      for (int s = 0; s < 4; ++s) {
        acc0 = __builtin_amdgcn_mfma_f32_16x16x32_bf16(c0[s], w8[s], acc0, 0, 0, 0);
        acc1 = __builtin_amdgcn_mfma_f32_16x16x32_bf16(c1[s], w8[s], acc1, 0, 0, 0);
      }
      *(f32x4*)(red + (wave * 2 + 0) * 260 + lane * 4) = acc0;
      *(f32x4*)(red + (wave * 2 + 1) * 260 + lane * 4) = acc1;
    }
    __syncthreads();
    if (owner) {
      U64s hs;
      float hv4[4];
      for (int jj = 0; jj < 4; ++jj) {
        float pin = 0.f, pfn = 0.f, po = 0.f;
        for (int w = 0; w < 8; ++w) {
          const float* rp = red + (w * 2 + omt) * 260 + org;
          pin += rp[(lhi + jj) * 4];
          pfn += rp[(lhi + 4 + jj) * 4];
          po  += rp[(lhi + 8 + jj) * 4];
        }
        float ov = opre_reg[jj] + po;  // NO sigmoid on o (per source)
        float hv = ov * tanh_(c_reg[jj]);
        pi_reg[jj] = pin; pf_reg[jj] = pfn;
        hs.s[jj] = f2bf(hv);
        hv4[jj] = hv;
      }
      u64* hd = (u64*)(a.hdst + (a.h_seq ? (size_t)t * BB * HH : 0) + ob * HH + j0);
      ST_AG(hd, hs.q);
      if (a.yout) *(float4*)(a.yout + (size_t)t * BB * HH + ob * HH + j0) =
                      make_float4(hv4[0], hv4[1], hv4[2], hv4[3]);
      if (t == TT - 1) {
        *(float4*)(a.hn_out + ob * HH + j0) = make_float4(hv4[0], hv4[1], hv4[2], hv4[3]);
        *(float4*)(a.cn_out + ob * HH + j0) =
            make_float4(c_reg[0], c_reg[1], c_reg[2], c_reg[3]);
      }
    }
    gbar(a.ctr, (++epoch) * 32);
  }
}

extern "C" void kernel_launch(void* const* d_in, const int* in_sizes, int n_in,
                              void* d_out, int out_size, void* d_ws, size_t ws_size,
                              hipStream_t stream) {
  const float* x    = (const float*)d_in[0];
  const float* wih0 = (const float*)d_in[1];
  const float* whh0 = (const float*)d_in[2];
  const float* wpi0 = (const float*)d_in[3];
  const float* wpf0 = (const float*)d_in[4];
  const float* wpo0 = (const float*)d_in[5];
  const float* wih1 = (const float*)d_in[6];
  const float* whh1 = (const float*)d_in[7];
  const float* wpi1 = (const float*)d_in[8];
  const float* wpf1 = (const float*)d_in[9];
  const float* wpo1 = (const float*)d_in[10];

  float* out = (float*)d_out;
  float* y1 = out;
  float* hn = out + (size_t)TT * BB * HH;
  float* cn = hn + 2 * BB * HH;

  char* ws = (char*)d_ws;
  short* xg    = (short*)(ws);                     // 134217728 B : [T][256][32][16]
  short* xbf   = (short*)(ws + 134217728ull);      //  33554432 B
  short* y0bf  = (short*)(ws + 167772160ull);      //  33554432 B
  short* wib0  = (short*)(ws + 201326592ull);      //   8388608 B
  short* wib1  = (short*)(ws + 209715200ull);      //   8388608 B
  short* h1bf  = (short*)(ws + 218103808ull);      //     65536 B
  short* cbf   = (short*)(ws + 218169344ull);      //     65536 B
  u32*   ctr   = (u32*)  (ws + 218234880ull);      //      2048 B : 8 counters, 256B apart

  f32_to_bf16_k<<<8192, 256, 0, stream>>>(x, xbf, 16777216);
  f32_to_bf16_k<<<2048, 256, 0, stream>>>(wih0, wib0, 4194304);
  f32_to_bf16_k<<<2048, 256, 0, stream>>>(wih1, wib1, 4194304);

  dim3 gproj(128, 32, 1);
  gemm_bt_k<<<gproj, 256, 0, stream>>>(xbf, wib0, xg, 16384, 4096, 1024);

  hipMemsetAsync(ctr, 0, 2048, stream);
  RecurArgs a0 = {whh0, wpi0, wpf0, wpo0, xg, y0bf, y0bf, nullptr, cbf, hn, cn, ctr, 1};
  recur_k<<<256, 512, 0, stream>>>(a0);

  gemm_bt_k<<<gproj, 256, 0, stream>>>(y0bf, wib1, xg, 16384, 4096, 1024);

  hipMemsetAsync(ctr, 0, 2048, stream);
  RecurArgs a1 = {whh1, wpi1, wpf1, wpo1, xg, h1bf, h1bf, y1, cbf, hn + BB * HH, cn + BB * HH, ctr, 0};
  recur_k<<<256, 512, 0, stream>>>(a1);
}

// Round 10
// 7013.028 us; speedup vs baseline: 3.8472x; 1.7956x over previous
//
#include <hip/hip_runtime.h>
#include <stdint.h>

typedef __attribute__((ext_vector_type(8))) short bf16x8;
typedef __attribute__((ext_vector_type(4))) float f32x4;
typedef unsigned int u32;
typedef unsigned long long u64;

#define TT 512
#define BB 32
#define HH 1024

#define LD_AG(p)     __hip_atomic_load((p), __ATOMIC_RELAXED, __HIP_MEMORY_SCOPE_AGENT)
#define ST_AG(p, v)  __hip_atomic_store((p), (v), __ATOMIC_RELAXED, __HIP_MEMORY_SCOPE_AGENT)
// 16B LLC (L2-bypass) load; caller waits via vmcnt(0)+sched_barrier (rule 18)
#define GLD16(dst, ptr) \
  asm volatile("global_load_dwordx4 %0, %1, off sc0 sc1" : "=v"(dst) : "v"(ptr))
// 16B cached load (read-only weights)
#define GLDC16(dst, ptr) \
  asm volatile("global_load_dwordx4 %0, %1, off" : "=v"(dst) : "v"(ptr))

__device__ __forceinline__ short f2bf(float f) {
  union { float f; u32 u; } v; v.f = f;
  u32 r = v.u + 0x7fffu + ((v.u >> 16) & 1u);
  return (short)(r >> 16);
}
__device__ __forceinline__ float bf2f(short s) {
  union { float f; u32 u; } v; v.u = ((u32)(unsigned short)s) << 16;
  return v.f;
}
__device__ __forceinline__ float sigmoid_(float x) { return 1.f / (1.f + __expf(-x)); }
__device__ __forceinline__ float tanh_(float x) {
  float cx = fminf(fmaxf(x, -15.f), 15.f);
  float e = __expf(2.f * cx);
  return (e - 1.f) / (e + 1.f);
}

union U64s { u64 q; short s[4]; };

// ---------------- fp32 -> bf16 convert ----------------
__global__ void f32_to_bf16_k(const float* __restrict__ in, short* __restrict__ out, int n) {
  int i = (blockIdx.x * blockDim.x + threadIdx.x) * 8;
  if (i + 8 > n) return;
  float4 a = *(const float4*)(in + i);
  float4 b = *(const float4*)(in + i + 4);
  bf16x8 o;
  o[0] = f2bf(a.x); o[1] = f2bf(a.y); o[2] = f2bf(a.z); o[3] = f2bf(a.w);
  o[4] = f2bf(b.x); o[5] = f2bf(b.y); o[6] = f2bf(b.z); o[7] = f2bf(b.w);
  *(bf16x8*)(out + i) = o;
}

// ---- proj GEMM (layer0 only): scatter into 128-block-major xga layout ----
// dst = ((t*128 + (col>>3))*32 + b)*32 + (colhalf)*16 + gate*4 + (col&3)
__launch_bounds__(256)
__global__ void gemm_bt_k(const short* __restrict__ A, const short* __restrict__ B,
                          short* __restrict__ C, int M, int N, int K) {
  __shared__ short As[128 * 64];
  __shared__ short Bs[128 * 64];
  const int tid = threadIdx.x;
  const int lane = tid & 63;
  const int wave = tid >> 6;
  const int m0 = blockIdx.x * 128, n0 = blockIdx.y * 128;
  const int wm = (wave >> 1) * 64, wn = (wave & 1) * 64;
  f32x4 acc[4][4];
  for (int i = 0; i < 4; i++)
    for (int j = 0; j < 4; j++) acc[i][j] = 0.f;
  bf16x8* Asv = (bf16x8*)As;
  bf16x8* Bsv = (bf16x8*)Bs;
  for (int k0 = 0; k0 < K; k0 += 64) {
    __syncthreads();
    for (int q = 0; q < 4; ++q) {
      int chunk = tid + q * 256;
      int row = chunk >> 3, col = (chunk & 7) * 8;
      Asv[chunk] = *(const bf16x8*)(A + (size_t)(m0 + row) * K + k0 + col);
      Bsv[chunk] = *(const bf16x8*)(B + (size_t)(n0 + row) * K + k0 + col);
    }
    __syncthreads();
    for (int ks = 0; ks < 2; ++ks) {
      int kk = ks * 32 + (lane >> 4) * 8;
      bf16x8 af[4], bfr[4];
      for (int i = 0; i < 4; i++) af[i] = *(const bf16x8*)(As + (wm + i * 16 + (lane & 15)) * 64 + kk);
      for (int j = 0; j < 4; j++) bfr[j] = *(const bf16x8*)(Bs + (wn + j * 16 + (lane & 15)) * 64 + kk);
      for (int i = 0; i < 4; i++)
        for (int j = 0; j < 4; j++)
          acc[i][j] = __builtin_amdgcn_mfma_f32_16x16x32_bf16(af[i], bfr[j], acc[i][j], 0, 0, 0);
    }
  }
  const int r4 = (lane >> 4) * 4, nn = lane & 15;
  for (int i = 0; i < 4; i++)
    for (int j = 0; j < 4; j++) {
      for (int r = 0; r < 4; r++) {
        int gm = m0 + wm + i * 16 + r4 + r;       // = t*32 + b
        int gn = n0 + wn + j * 16 + nn;           // = gate*1024 + col
        int tt = gm >> 5, b = gm & 31;
        int g = gn >> 10, col = gn & 1023;
        int blk = col >> 3, c8 = col & 7;
        size_t dst = (((size_t)tt * 128 + blk) * 32 + b) * 32 + (c8 >> 2) * 16 + g * 4 + (c8 & 3);
        C[dst] = f2bf(acc[i][j][r]);
      }
    }
}

// ---- group-local counter barrier: 8 counters/group, 16 blocks each ----
__device__ __forceinline__ void gbar(u32* ctr, int gbid, u32 target) {
  __syncthreads();
  if (threadIdx.x == 0) {
    asm volatile("s_waitcnt vmcnt(0)" ::: "memory");  // wave0 data stores at LLC first
    __hip_atomic_fetch_add(ctr + (gbid & 7) * 64, 1u,
                           __ATOMIC_RELAXED, __HIP_MEMORY_SCOPE_AGENT);
  }
  if (threadIdx.x < 64) {
    for (;;) {
      u32 v = (threadIdx.x < 8) ? LD_AG(ctr + threadIdx.x * 64) : 0xffffffffu;
      if (__all(v >= target)) break;
    }
  }
  __syncthreads();
}

// ------------- fused two-layer persistent kernel (256 blocks) --------------
// blocks 0-127: layer 0 (group A); blocks 128-255: layer 1 (group B).
// B runs one step behind A, gated by polling ctrA (A never waits on B).
struct R2Args {
  const float *Whh0, *Wpi0, *Wpf0, *Wpo0;
  const float *Whh1, *Wpi1, *Wpf1, *Wpo1;
  const short* xga;   // [T][128][32][32] bf16 (layer0 input proj, block-major)
  const short* wib1;  // [4096][1024] bf16 W_ih1 (cached reads)
  short* y0bf;        // [T][32][1024] layer0 h history (LLC exchange)
  short* h1bf;        // [32][1024] layer1 h (zeroed before launch)
  short* cbf0;        // [32][1024] c exchange A
  short* cbf1;        // [32][1024] c exchange B
  float* yout;        // [T][32][1024] fp32 final output
  float *hn0, *cn0, *hn1, *cn1;
  u32 *ctrA, *ctrB;   // 8 counters each, 256B apart (pre-zeroed)
};

__launch_bounds__(512)
__global__ void recur2_k(R2Args a) {
  // LDS: 56 weight rows x 1024 bf16 (114.7KB) + red 32x260 f32 (33.3KB) = 148KB
  __shared__ short wlds[56 * 1024];
  __shared__ float red[32 * 260];
  const int tid = threadIdx.x;
  const int grp = blockIdx.x >> 7;
  const int gbid = blockIdx.x & 127;
  const int lane = tid & 63;
  const int wave = tid >> 6;
  const int j0 = gbid * 8;
  const int l15 = lane & 15, l4 = lane >> 4;

  const float* Whh = grp ? a.Whh1 : a.Whh0;
  const float* Wpi = grp ? a.Wpi1 : a.Wpi0;
  const float* Wpf = grp ? a.Wpf1 : a.Wpf0;
  const float* Wpo = grp ? a.Wpo1 : a.Wpo0;
  short* cbf = grp ? a.cbf1 : a.cbf0;
  u32* ctro = grp ? a.ctrB : a.ctrA;

  // weights -> LDS (bf16, per-row swizzle cc^(row&7)):
  // rows 0-31: Whh row (r>>3)*1024 + j0 + (r&7)   [MFMA n = gate*8 + col]
  // rows 32-55: r2=row-32: p=r2>>3 (pi,pf,po), col=r2&7
  for (int ch = tid; ch < 56 * 128; ch += 512) {
    int row = ch >> 7, cc = ch & 127;
    const float* src;
    if (row < 32) {
      src = Whh + (size_t)((row >> 3) * 1024 + j0 + (row & 7)) * 1024;
    } else {
      int r2 = row - 32, p = r2 >> 3;
      const float* W = (p == 0) ? Wpi : (p == 1 ? Wpf : Wpo);
      src = W + (size_t)(j0 + (r2 & 7)) * 1024;
    }
    float4 f0 = *(const float4*)(src + cc * 8);
    float4 f1 = *(const float4*)(src + cc * 8 + 4);
    bf16x8 o;
    o[0] = f2bf(f0.x); o[1] = f2bf(f0.y); o[2] = f2bf(f0.z); o[3] = f2bf(f0.w);
    o[4] = f2bf(f1.x); o[5] = f2bf(f1.y); o[6] = f2bf(f1.z); o[7] = f2bf(f1.w);
    *(bf16x8*)(wlds + row * 1024 + (cc ^ (row & 7)) * 8) = o;
  }
  __syncthreads();

  // 64 owner threads: (batch ob, column-half oh) -> columns j0+oh*4 .. +3
  const bool owner = tid < 64;
  const int ob = tid & 31;
  const int oh = (tid >> 5) & 1;
  const int omt = (ob >> 4) & 1;
  const int lhi = ((ob & 15) >> 2) * 16;
  const int org = ob & 3;
  float c_reg[4] = {0, 0, 0, 0}, pi_reg[4] = {0, 0, 0, 0}, pf_reg[4] = {0, 0, 0, 0};
  float opre_reg[4] = {0, 0, 0, 0};
  u32 epoch = 0;

  for (int t = 0; t < TT; ++t) {
    bf16x8 xv0 = 0, xv1 = 0;
    if (grp == 0 && owner) {
      const short* xgp = a.xga + (((size_t)t * 128 + gbid) * 32 + ob) * 32 + oh * 16;
      xv0 = *(const bf16x8*)(xgp);      // gates i,f (4 cols each)
      xv1 = *(const bf16x8*)(xgp + 8);  // gates g,o
    }
    // ---------------- phase 1: gates; c update ----------------
    bool haveRed;
    {
      f32x4 acc[2][2] = {{0.f, 0.f}, {0.f, 0.f}};
      if (grp == 0) {
        haveRed = (t > 0);
        if (haveRed) {
          const short* hb = a.y0bf + (size_t)(t - 1) * BB * HH;
          bf16x8 hf[2][4], wf[2][4];
#pragma unroll
          for (int s = 0; s < 4; ++s) {
            int k = wave * 128 + s * 32 + l4 * 8;
            GLD16(hf[0][s], hb + (size_t)l15 * HH + k);
            GLD16(hf[1][s], hb + (size_t)(16 + l15) * HH + k);
          }
#pragma unroll
          for (int rg = 0; rg < 2; ++rg)
#pragma unroll
            for (int s = 0; s < 4; ++s) {
              int k = wave * 128 + s * 32 + l4 * 8;
              wf[rg][s] = *(const bf16x8*)(wlds + (rg * 16 + l15) * 1024 + ((k >> 3) ^ (l15 & 7)) * 8);
            }
          asm volatile("s_waitcnt vmcnt(0)" ::: "memory");
          __builtin_amdgcn_sched_barrier(0);
#pragma unroll
          for (int s = 0; s < 4; ++s)
#pragma unroll
            for (int rg = 0; rg < 2; ++rg)
#pragma unroll
              for (int hl = 0; hl < 2; ++hl)
                acc[rg][hl] = __builtin_amdgcn_mfma_f32_16x16x32_bf16(hf[hl][s], wf[rg][s], acc[rg][hl], 0, 0, 0);
        }
      } else {
        haveRed = true;
        bf16x8 h1f[2][4], wg[2][4], wl[2][4], yf[2][4];
#pragma unroll
        for (int s = 0; s < 4; ++s) {
          int k = wave * 128 + s * 32 + l4 * 8;
          GLD16(h1f[0][s], a.h1bf + (size_t)l15 * HH + k);
          GLD16(h1f[1][s], a.h1bf + (size_t)(16 + l15) * HH + k);
        }
#pragma unroll
        for (int rg = 0; rg < 2; ++rg) {
          int n = rg * 16 + l15;
          const short* wrow = a.wib1 + (size_t)((n >> 3) * 1024 + j0 + (n & 7)) * 1024;
#pragma unroll
          for (int s = 0; s < 4; ++s) {
            int k = wave * 128 + s * 32 + l4 * 8;
            GLDC16(wg[rg][s], wrow + k);
          }
        }
#pragma unroll
        for (int rg = 0; rg < 2; ++rg)
#pragma unroll
          for (int s = 0; s < 4; ++s) {
            int k = wave * 128 + s * 32 + l4 * 8;
            wl[rg][s] = *(const bf16x8*)(wlds + (rg * 16 + l15) * 1024 + ((k >> 3) ^ (l15 & 7)) * 8);
          }
        // wait for layer0 to finish step t (h written before A's phase-2 arrival)
        if (tid < 64) {
          u32 tgt = (u32)(t + 1) * 32u;
          for (;;) {
            u32 v = (lane < 8) ? LD_AG(a.ctrA + lane * 64) : 0xffffffffu;
            if (__all(v >= tgt)) break;
          }
        }
        __syncthreads();
        const short* yb = a.y0bf + (size_t)t * BB * HH;
#pragma unroll
        for (int s = 0; s < 4; ++s) {
          int k = wave * 128 + s * 32 + l4 * 8;
          GLD16(yf[0][s], yb + (size_t)l15 * HH + k);
          GLD16(yf[1][s], yb + (size_t)(16 + l15) * HH + k);
        }
        asm volatile("s_waitcnt vmcnt(0)" ::: "memory");
        __builtin_amdgcn_sched_barrier(0);
#pragma unroll
        for (int s = 0; s < 4; ++s)
#pragma unroll
          for (int rg = 0; rg < 2; ++rg)
#pragma unroll
            for (int hl = 0; hl < 2; ++hl) {
              acc[rg][hl] = __builtin_amdgcn_mfma_f32_16x16x32_bf16(yf[hl][s], wg[rg][s], acc[rg][hl], 0, 0, 0);
              acc[rg][hl] = __builtin_amdgcn_mfma_f32_16x16x32_bf16(h1f[hl][s], wl[rg][s], acc[rg][hl], 0, 0, 0);
            }
      }
      if (haveRed) {
#pragma unroll
        for (int rg = 0; rg < 2; ++rg)
#pragma unroll
          for (int hl = 0; hl < 2; ++hl)
            *(f32x4*)(red + (wave * 4 + rg * 2 + hl) * 260 + lane * 4) = acc[rg][hl];
      }
    }
    __syncthreads();
    if (owner) {
      U64s cs;
      for (int jj = 0; jj < 4; ++jj) {
        int col = oh * 4 + jj;
        float gi = 0.f, gf = 0.f, gg = 0.f, go = 0.f;
        if (haveRed) {
          for (int w = 0; w < 8; ++w) {
            const float* r0 = red + (w * 4 + omt) * 260 + org;      // rowgroup 0 (gates i,f)
            const float* r1 = red + (w * 4 + 2 + omt) * 260 + org;  // rowgroup 1 (gates g,o)
            gi += r0[(lhi + col) * 4];
            gf += r0[(lhi + 8 + col) * 4];
            gg += r1[(lhi + col) * 4];
            go += r1[(lhi + 8 + col) * 4];
          }
        }
        float xi = 0.f, xf = 0.f, xgv = 0.f, xo = 0.f;
        if (grp == 0) { xi = bf2f(xv0[jj]); xf = bf2f(xv0[4 + jj]); xgv = bf2f(xv1[jj]); xo = bf2f(xv1[4 + jj]); }
        float iv = sigmoid_(gi + xi + pi_reg[jj]);
        float fv = sigmoid_(gf + xf + pf_reg[jj]);
        float gv = tanh_(gg + xgv);
        float cnew = fv * c_reg[jj] + iv * gv;
        opre_reg[jj] = go + xo;
        c_reg[jj] = cnew;
        cs.s[jj] = f2bf(cnew);
      }
      ST_AG((u64*)(cbf + ob * HH + j0 + oh * 4), cs.q);
    }
    gbar(ctro, gbid, (++epoch) * 16);
    // ---------------- phase 2: peephole GEMV; h update ----------------
    {
      bf16x8 cf[2][4], wf2[2][4];
#pragma unroll
      for (int s = 0; s < 4; ++s) {
        int k = wave * 128 + s * 32 + l4 * 8;
        GLD16(cf[0][s], cbf + (size_t)l15 * HH + k);
        GLD16(cf[1][s], cbf + (size_t)(16 + l15) * HH + k);
      }
#pragma unroll
      for (int s = 0; s < 4; ++s) {
        int k = wave * 128 + s * 32 + l4 * 8;
        int cch = k >> 3;
        wf2[0][s] = *(const bf16x8*)(wlds + (32 + l15) * 1024 + (cch ^ (l15 & 7)) * 8);
        int r1 = 48 + (l15 & 7);  // po rows; lanes 8-15 duplicate (cols 8-15 of rg1 unused)
        wf2[1][s] = *(const bf16x8*)(wlds + r1 * 1024 + (cch ^ (l15 & 7)) * 8);
      }
      asm volatile("s_waitcnt vmcnt(0)" ::: "memory");
      __builtin_amdgcn_sched_barrier(0);
      f32x4 acc2[2][2] = {{0.f, 0.f}, {0.f, 0.f}};
#pragma unroll
      for (int s = 0; s < 4; ++s)
#pragma unroll
        for (int rg = 0; rg < 2; ++rg)
#pragma unroll
          for (int hl = 0; hl < 2; ++hl)
            acc2[rg][hl] = __builtin_amdgcn_mfma_f32_16x16x32_bf16(cf[hl][s], wf2[rg][s], acc2[rg][hl], 0, 0, 0);
#pragma unroll
      for (int rg = 0; rg < 2; ++rg)
#pragma unroll
        for (int hl = 0; hl < 2; ++hl)
          *(f32x4*)(red + (wave * 4 + rg * 2 + hl) * 260 + lane * 4) = acc2[rg][hl];
    }
    __syncthreads();
    if (owner) {
      U64s hs;
      float hv4[4];
      for (int jj = 0; jj < 4; ++jj) {
        int col = oh * 4 + jj;
        float pin = 0.f, pfn = 0.f, po = 0.f;
        for (int w = 0; w < 8; ++w) {
          const float* r0 = red + (w * 4 + omt) * 260 + org;
          const float* r1 = red + (w * 4 + 2 + omt) * 260 + org;
          pin += r0[(lhi + col) * 4];
          pfn += r0[(lhi + 8 + col) * 4];
          po  += r1[(lhi + col) * 4];
        }
        float ov = opre_reg[jj] + po;  // NO sigmoid on o (per source)
        float hv = ov * tanh_(c_reg[jj]);
        pi_reg[jj] = pin; pf_reg[jj] = pfn;
        hs.s[jj] = f2bf(hv);
        hv4[jj] = hv;
      }
      if (grp == 0) {
        ST_AG((u64*)(a.y0bf + (size_t)t * BB * HH + ob * HH + j0 + oh * 4), hs.q);
        if (t == TT - 1) {
          *(float4*)(a.hn0 + ob * HH + j0 + oh * 4) = make_float4(hv4[0], hv4[1], hv4[2], hv4[3]);
          *(float4*)(a.cn0 + ob * HH + j0 + oh * 4) = make_float4(c_reg[0], c_reg[1], c_reg[2], c_reg[3]);
        }
      } else {
        ST_AG((u64*)(a.h1bf + ob * HH + j0 + oh * 4), hs.q);
        *(float4*)(a.yout + (size_t)t * BB * HH + ob * HH + j0 + oh * 4) =
            make_float4(hv4[0], hv4[1], hv4[2], hv4[3]);
        if (t == TT - 1) {
          *(float4*)(a.hn1 + ob * HH + j0 + oh * 4) = make_float4(hv4[0], hv4[1], hv4[2], hv4[3]);
          *(float4*)(a.cn1 + ob * HH + j0 + oh * 4) = make_float4(c_reg[0], c_reg[1], c_reg[2], c_reg[3]);
        }
      }
    }
    gbar(ctro, gbid, (++epoch) * 16);
  }
}

extern "C" void kernel_launch(void* const* d_in, const int* in_sizes, int n_in,
                              void* d_out, int out_size, void* d_ws, size_t ws_size,
                              hipStream_t stream) {
  const float* x    = (const float*)d_in[0];
  const float* wih0 = (const float*)d_in[1];
  const float* whh0 = (const float*)d_in[2];
  const float* wpi0 = (const float*)d_in[3];
  const float* wpf0 = (const float*)d_in[4];
  const float* wpo0 = (const float*)d_in[5];
  const float* wih1 = (const float*)d_in[6];
  const float* whh1 = (const float*)d_in[7];
  const float* wpi1 = (const float*)d_in[8];
  const float* wpf1 = (const float*)d_in[9];
  const float* wpo1 = (const float*)d_in[10];

  float* out = (float*)d_out;
  float* y1 = out;
  float* hn = out + (size_t)TT * BB * HH;
  float* cn = hn + 2 * BB * HH;

  char* ws = (char*)d_ws;
  short* xga  = (short*)(ws);                     // 134217728 B : [T][128][32][32]
  short* xbf  = (short*)(ws + 134217728ull);      //  33554432 B : x bf16 (reused as y0bf)
  short* wib0 = (short*)(ws + 167772160ull);      //   8388608 B
  short* wib1 = (short*)(ws + 176160768ull);      //   8388608 B
  short* h1bf = (short*)(ws + 184549376ull);      //     65536 B
  short* cbf0 = (short*)(ws + 184614912ull);      //     65536 B
  short* cbf1 = (short*)(ws + 184680448ull);      //     65536 B
  u32*   ctrA = (u32*)  (ws + 184745984ull);      //      2048 B
  u32*   ctrB = (u32*)  (ws + 184748032ull);      //      2048 B
  short* y0bf = xbf;  // xbf fully consumed by GEMM before recur2 starts

  f32_to_bf16_k<<<8192, 256, 0, stream>>>(x, xbf, 16777216);
  f32_to_bf16_k<<<2048, 256, 0, stream>>>(wih0, wib0, 4194304);
  f32_to_bf16_k<<<2048, 256, 0, stream>>>(wih1, wib1, 4194304);

  dim3 gproj(128, 32, 1);
  gemm_bt_k<<<gproj, 256, 0, stream>>>(xbf, wib0, xga, 16384, 4096, 1024);

  hipMemsetAsync(ctrA, 0, 4096, stream);     // ctrA + ctrB contiguous
  hipMemsetAsync(h1bf, 0, 65536, stream);    // layer1 h starts at zero

  R2Args a;
  a.Whh0 = whh0; a.Wpi0 = wpi0; a.Wpf0 = wpf0; a.Wpo0 = wpo0;
  a.Whh1 = whh1; a.Wpi1 = wpi1; a.Wpf1 = wpf1; a.Wpo1 = wpo1;
  a.xga = xga; a.wib1 = wib1;
  a.y0bf = y0bf; a.h1bf = h1bf; a.cbf0 = cbf0; a.cbf1 = cbf1;
  a.yout = y1;
  a.hn0 = hn; a.cn0 = cn; a.hn1 = hn + BB * HH; a.cn1 = cn + BB * HH;
  a.ctrA = ctrA; a.ctrB = ctrB;
  recur2_k<<<256, 512, 0, stream>>>(a);
}